// Round 1
// baseline (439.388 us; speedup 1.0000x reference)
//
#include <hip/hip_runtime.h>

#define SEQ 512
#define BATCH 8192
#define HDIM 10

__device__ __forceinline__ float fast_sigmoid(float z) {
    // sigmoid(z) = 1 / (1 + e^-z); __expf -> v_exp_f32, rcp -> v_rcp_f32
    return __builtin_amdgcn_rcpf(1.0f + __expf(-z));
}

__device__ __forceinline__ float fast_tanh(float z) {
    // tanh(z) = 1 - 2/(e^{2z} + 1); saturates correctly for |z| large
    return 1.0f - 2.0f * __builtin_amdgcn_rcpf(__expf(2.0f * z) + 1.0f);
}

// 16 lanes per batch element: lanes 0..9 own hidden units 0..9, lanes 10..15
// are dummies (clamped to unit 0; their results are never read).
// Each lane computes the 4 gates (i,f,g,o) of its unit for both LSTM layers,
// keeps c lane-local, and broadcasts h group-wide via __shfl each step.
__global__ __launch_bounds__(256, 2) void lstm2_fc_kernel(
    const float* __restrict__ x,
    const float* __restrict__ w_ih0, const float* __restrict__ w_hh0,
    const float* __restrict__ b_ih0, const float* __restrict__ b_hh0,
    const float* __restrict__ w_ih1, const float* __restrict__ w_hh1,
    const float* __restrict__ b_ih1, const float* __restrict__ b_hh1,
    const float* __restrict__ fc_w, const float* __restrict__ fc_b,
    float* __restrict__ out)
{
    const int lane16 = threadIdx.x & 15;                 // unit slot in group
    const int b      = blockIdx.x * 16 + (threadIdx.x >> 4);
    const int u      = (lane16 < HDIM) ? lane16 : 0;     // clamp dummies
    const int lane   = threadIdx.x & 63;
    const int gbase  = lane & 48;                        // 16-lane group base in wave

    // gate rows in torch order: i, f, g, o
    const int rows[4] = { u, 10 + u, 20 + u, 30 + u };

    // ---- load loop-invariant weights into registers ----
    float wi0[4][2], wh0[4][HDIM], bb0[4];
    float wi1[4][HDIM], wh1[4][HDIM], bb1[4];
    #pragma unroll
    for (int g = 0; g < 4; ++g) {
        const int r = rows[g];
        wi0[g][0] = w_ih0[r * 2 + 0];
        wi0[g][1] = w_ih0[r * 2 + 1];
        bb0[g]    = b_ih0[r] + b_hh0[r];
        bb1[g]    = b_ih1[r] + b_hh1[r];
        #pragma unroll
        for (int j = 0; j < HDIM; ++j) {
            wh0[g][j] = w_hh0[r * HDIM + j];
            wi1[g][j] = w_ih1[r * HDIM + j];
            wh1[g][j] = w_hh1[r * HDIM + j];
        }
    }

    // ---- state ----
    float h1[HDIM], h2[HDIM];
    #pragma unroll
    for (int j = 0; j < HDIM; ++j) { h1[j] = 0.0f; h2[j] = 0.0f; }
    float c1 = 0.0f, c2 = 0.0f;

    // prefetch x[t=0]
    float2 xv = *reinterpret_cast<const float2*>(x + ((size_t)0 * BATCH + b) * 2);

    for (int t = 0; t < SEQ; ++t) {
        // prefetch next timestep's x (clamped on last iter; value unused)
        const int tn = (t + 1 < SEQ) ? (t + 1) : t;
        const float2 xnext =
            *reinterpret_cast<const float2*>(x + ((size_t)tn * BATCH + b) * 2);

        // ---- layer 0 gates ----
        float z[4];
        #pragma unroll
        for (int g = 0; g < 4; ++g) {
            float acc = bb0[g] + wi0[g][0] * xv.x + wi0[g][1] * xv.y;
            #pragma unroll
            for (int j = 0; j < HDIM; ++j) acc += wh0[g][j] * h1[j];
            z[g] = acc;
        }
        {
            const float ig = fast_sigmoid(z[0]);
            const float fg = fast_sigmoid(z[1]);
            const float gg = fast_tanh(z[2]);
            const float og = fast_sigmoid(z[3]);
            c1 = fg * c1 + ig * gg;
            const float h1o = og * fast_tanh(c1);
            #pragma unroll
            for (int j = 0; j < HDIM; ++j) h1[j] = __shfl(h1o, gbase + j, 64);
        }

        // ---- layer 1 gates ----
        #pragma unroll
        for (int g = 0; g < 4; ++g) {
            float acc = bb1[g];
            #pragma unroll
            for (int j = 0; j < HDIM; ++j) acc += wi1[g][j] * h1[j];
            #pragma unroll
            for (int j = 0; j < HDIM; ++j) acc += wh1[g][j] * h2[j];
            z[g] = acc;
        }
        {
            const float ig = fast_sigmoid(z[0]);
            const float fg = fast_sigmoid(z[1]);
            const float gg = fast_tanh(z[2]);
            const float og = fast_sigmoid(z[3]);
            c2 = fg * c2 + ig * gg;
            const float h2o = og * fast_tanh(c2);
            #pragma unroll
            for (int j = 0; j < HDIM; ++j) h2[j] = __shfl(h2o, gbase + j, 64);
        }

        xv = xnext;
    }

    // ---- final FC: out[b][k] = fc_b[k] + sum_j fc_w[k][j] * h2[j] ----
    if (lane16 < 2) {
        float acc = fc_b[lane16];
        #pragma unroll
        for (int j = 0; j < HDIM; ++j) acc += fc_w[lane16 * HDIM + j] * h2[j];
        out[(size_t)b * 2 + lane16] = acc;
    }
}

extern "C" void kernel_launch(void* const* d_in, const int* in_sizes, int n_in,
                              void* d_out, int out_size, void* d_ws, size_t ws_size,
                              hipStream_t stream) {
    const float* x     = (const float*)d_in[0];
    const float* w_ih0 = (const float*)d_in[1];
    const float* w_hh0 = (const float*)d_in[2];
    const float* b_ih0 = (const float*)d_in[3];
    const float* b_hh0 = (const float*)d_in[4];
    const float* w_ih1 = (const float*)d_in[5];
    const float* w_hh1 = (const float*)d_in[6];
    const float* b_ih1 = (const float*)d_in[7];
    const float* b_hh1 = (const float*)d_in[8];
    const float* fc_w  = (const float*)d_in[9];
    const float* fc_b  = (const float*)d_in[10];
    float* out = (float*)d_out;

    const int threads = 256;                  // 16 batch elements per block
    const int blocks  = BATCH / 16;           // 512 blocks -> 2 blocks/CU
    lstm2_fc_kernel<<<blocks, threads, 0, stream>>>(
        x, w_ih0, w_hh0, b_ih0, b_hh0,
        w_ih1, w_hh1, b_ih1, b_hh1, fc_w, fc_b, out);
}

// Round 2
// 366.795 us; speedup vs baseline: 1.1979x; 1.1979x over previous
//
#include <hip/hip_runtime.h>

#define SEQ 512
#define BATCH 8192
#define HDIM 10

#define LOG2E 1.44269504088896340736f

// r = rcp(1 + exp2(zt)).  Callers pre-scale z:
//   sigmoid(z) = r     with zt = -log2e * z   (folded into weights)
//   tanh(z)    = 1-2r  with zt = +2log2e * z  (folded into weights)
__device__ __forceinline__ float gate_r(float zt) {
    return __builtin_amdgcn_rcpf(1.0f + __builtin_amdgcn_exp2f(zt));
}

// 16 lanes per batch element: lanes 0..9 own hidden units 0..9 (lanes 10..15
// dummy, clamped to unit 0 — free in wave-issue terms). Each lane computes the
// 4 gates of its unit for both layers; c is lane-local; h broadcast via shfl.
//
// Software pipeline: iteration t computes layer0[t+1] (reads h1[t], x[t+1])
// then layer1[t] (reads h1[t], h2[t-1]); each broadcast is issued ~70+ instrs
// before its first consumer, hiding ds_bpermute latency completely.
__global__ __launch_bounds__(256, 2) void lstm2_fc_kernel(
    const float* __restrict__ x,
    const float* __restrict__ w_ih0, const float* __restrict__ w_hh0,
    const float* __restrict__ b_ih0, const float* __restrict__ b_hh0,
    const float* __restrict__ w_ih1, const float* __restrict__ w_hh1,
    const float* __restrict__ b_ih1, const float* __restrict__ b_hh1,
    const float* __restrict__ fc_w, const float* __restrict__ fc_b,
    float* __restrict__ out)
{
    const int lane16 = threadIdx.x & 15;
    const int b      = blockIdx.x * 16 + (threadIdx.x >> 4);
    const int u      = (lane16 < HDIM) ? lane16 : 0;
    const int gbase  = (threadIdx.x & 63) & 48;   // 16-lane group base in wave

    // torch gate order: i, f, g, o.  Pre-scale so activation needs no mul:
    const int   rows[4] = { u, 10 + u, 20 + u, 30 + u };
    const float gs[4]   = { -LOG2E, -LOG2E, 2.0f * LOG2E, -LOG2E };

    // ---- load loop-invariant weights into registers (pre-scaled) ----
    float wi0[4][2], wh0[4][HDIM], bb0[4];
    float wi1[4][HDIM], wh1[4][HDIM], bb1[4];
    #pragma unroll
    for (int g = 0; g < 4; ++g) {
        const int r = rows[g];
        const float s = gs[g];
        wi0[g][0] = s * w_ih0[r * 2 + 0];
        wi0[g][1] = s * w_ih0[r * 2 + 1];
        bb0[g]    = s * (b_ih0[r] + b_hh0[r]);
        bb1[g]    = s * (b_ih1[r] + b_hh1[r]);
        #pragma unroll
        for (int j = 0; j < HDIM; ++j) {
            wh0[g][j] = s * w_hh0[r * HDIM + j];
            wi1[g][j] = s * w_ih1[r * HDIM + j];
            wh1[g][j] = s * w_hh1[r * HDIM + j];
        }
    }

    // ---- state ----
    float h1[HDIM], h2[HDIM];
    #pragma unroll
    for (int j = 0; j < HDIM; ++j) { h1[j] = 0.0f; h2[j] = 0.0f; }
    float c1 = 0.0f, c2 = 0.0f;

    // ---- prologue: layer0 at t=0 (h1 == 0, so only x terms) ----
    {
        const float2 x0 = *reinterpret_cast<const float2*>(x + (size_t)b * 2);
        float z[4];
        #pragma unroll
        for (int g = 0; g < 4; ++g)
            z[g] = bb0[g] + wi0[g][0] * x0.x + wi0[g][1] * x0.y;
        const float ig = gate_r(z[0]);
        const float fg = gate_r(z[1]);
        const float gg = fmaf(-2.0f, gate_r(z[2]), 1.0f);
        const float og = gate_r(z[3]);
        c1 = ig * gg;                         // c was 0: f*0 + i*g
        const float th = fmaf(-2.0f, gate_r(2.0f * LOG2E * c1), 1.0f);
        const float h1o = og * th;
        #pragma unroll
        for (int j = 0; j < HDIM; ++j) h1[j] = __shfl(h1o, gbase + j, 64);
    }

    float2 xv = *reinterpret_cast<const float2*>(x + ((size_t)1 * BATCH + b) * 2);

    // ---- main loop: iter t computes layer0[t+1] and layer1[t] ----
    for (int t = 0; t < SEQ - 1; ++t) {
        const int tn = (t + 2 < SEQ) ? (t + 2) : (SEQ - 1);
        const float2 xnext =
            *reinterpret_cast<const float2*>(x + ((size_t)tn * BATCH + b) * 2);

        // -- layer0 gates for step t+1 (reads h1[t], xv = x[t+1]) --
        float z0[4];
        #pragma unroll
        for (int g = 0; g < 4; ++g) {
            float acc = bb0[g] + wi0[g][0] * xv.x + wi0[g][1] * xv.y;
            #pragma unroll
            for (int j = 0; j < HDIM; ++j) acc = fmaf(wh0[g][j], h1[j], acc);
            z0[g] = acc;
        }
        const float i0 = gate_r(z0[0]);
        const float f0 = gate_r(z0[1]);
        const float g0 = fmaf(-2.0f, gate_r(z0[2]), 1.0f);
        const float o0 = gate_r(z0[3]);
        c1 = f0 * c1 + i0 * g0;
        const float th0 = fmaf(-2.0f, gate_r(2.0f * LOG2E * c1), 1.0f);
        const float h1o = o0 * th0;

        // issue h1[t+1] broadcast now; consumers are ~80+ instrs away
        float h1n[HDIM];
        #pragma unroll
        for (int j = 0; j < HDIM; ++j) h1n[j] = __shfl(h1o, gbase + j, 64);

        // -- layer1 gates for step t (reads h1[t] (old regs), h2[t-1]) --
        float z1[4];
        #pragma unroll
        for (int g = 0; g < 4; ++g) {
            float acc = bb1[g];
            #pragma unroll
            for (int j = 0; j < HDIM; ++j) acc = fmaf(wi1[g][j], h1[j], acc);
            #pragma unroll
            for (int j = 0; j < HDIM; ++j) acc = fmaf(wh1[g][j], h2[j], acc);
            z1[g] = acc;
        }
        const float i1 = gate_r(z1[0]);
        const float f1 = gate_r(z1[1]);
        const float g1 = fmaf(-2.0f, gate_r(z1[2]), 1.0f);
        const float o1 = gate_r(z1[3]);
        c2 = f1 * c2 + i1 * g1;
        const float th1 = fmaf(-2.0f, gate_r(2.0f * LOG2E * c2), 1.0f);
        const float h2o = o1 * th1;

        // issue h2[t] broadcast; consumed next iteration after layer0 block
        #pragma unroll
        for (int j = 0; j < HDIM; ++j) h2[j] = __shfl(h2o, gbase + j, 64);

        // rotate pipeline registers
        #pragma unroll
        for (int j = 0; j < HDIM; ++j) h1[j] = h1n[j];
        xv = xnext;
    }

    // ---- epilogue: layer1 at t = SEQ-1, then FC ----
    {
        float z1[4];
        #pragma unroll
        for (int g = 0; g < 4; ++g) {
            float acc = bb1[g];
            #pragma unroll
            for (int j = 0; j < HDIM; ++j) acc = fmaf(wi1[g][j], h1[j], acc);
            #pragma unroll
            for (int j = 0; j < HDIM; ++j) acc = fmaf(wh1[g][j], h2[j], acc);
            z1[g] = acc;
        }
        const float i1 = gate_r(z1[0]);
        const float f1 = gate_r(z1[1]);
        const float g1 = fmaf(-2.0f, gate_r(z1[2]), 1.0f);
        const float o1 = gate_r(z1[3]);
        c2 = f1 * c2 + i1 * g1;
        const float th1 = fmaf(-2.0f, gate_r(2.0f * LOG2E * c2), 1.0f);
        const float h2o = o1 * th1;
        #pragma unroll
        for (int j = 0; j < HDIM; ++j) h2[j] = __shfl(h2o, gbase + j, 64);
    }

    if (lane16 < 2) {
        float acc = fc_b[lane16];
        #pragma unroll
        for (int j = 0; j < HDIM; ++j) acc = fmaf(fc_w[lane16 * HDIM + j], h2[j], acc);
        out[(size_t)b * 2 + lane16] = acc;
    }
}

extern "C" void kernel_launch(void* const* d_in, const int* in_sizes, int n_in,
                              void* d_out, int out_size, void* d_ws, size_t ws_size,
                              hipStream_t stream) {
    const float* x     = (const float*)d_in[0];
    const float* w_ih0 = (const float*)d_in[1];
    const float* w_hh0 = (const float*)d_in[2];
    const float* b_ih0 = (const float*)d_in[3];
    const float* b_hh0 = (const float*)d_in[4];
    const float* w_ih1 = (const float*)d_in[5];
    const float* w_hh1 = (const float*)d_in[6];
    const float* b_ih1 = (const float*)d_in[7];
    const float* b_hh1 = (const float*)d_in[8];
    const float* fc_w  = (const float*)d_in[9];
    const float* fc_b  = (const float*)d_in[10];
    float* out = (float*)d_out;

    const int threads = 256;                  // 16 batch elements per block
    const int blocks  = BATCH / 16;           // 512 blocks -> 2 blocks/CU
    lstm2_fc_kernel<<<blocks, threads, 0, stream>>>(
        x, w_ih0, w_hh0, b_ih0, b_hh0,
        w_ih1, w_hh1, b_ih1, b_hh1, fc_w, fc_b, out);
}